// Round 1
// baseline (541.971 us; speedup 1.0000x reference)
//
#include <hip/hip_runtime.h>
#include <math.h>

// Problem constants
#define BQ 64
#define NOBJ 5
#define CIN 3
#define IMG_H 64
#define IMG_W 96
#define OH 32
#define OW 48
#define OC 128
#define NPAIR 25
#define PP 4
#define CONV_OUT 32

// Tiling
#define TILE_OH 4            // output rows per block
#define NTILES (OH / TILE_OH)
#define IN_ROWS (TILE_OH * 2 + 1)   // 9 input rows needed
#define LDS_STRIDE 100       // >= IMG_W + 2 pad cols, padded for safety

// S layout in workspace: [2][BQ][NPAIR][OC] floats = 1.6 MB
// S[src][b][i*5+j][oc] = sum over 32x48 positions of relu(convA(s_i)+convB(s_j)+bias)

__global__ __launch_bounds__(256) void conv_pair_reduce(
    const float* __restrict__ state,
    const float* __restrict__ state_next,
    const float* __restrict__ conv_w,
    const float* __restrict__ conv_b,
    float* __restrict__ S)
{
    __shared__ float sIn[NOBJ * CIN * IN_ROWS * LDS_STRIDE]; // 13500 floats = 54 KB

    const int tid  = threadIdx.x;
    const int tile = blockIdx.x;   // 0..7
    const int b    = blockIdx.y;   // 0..63
    const int src  = blockIdx.z;   // 0..1

    const float* g = (src == 0 ? state : state_next)
                   + (size_t)b * NOBJ * CIN * IMG_H * IMG_W;

    const int r0 = tile * (TILE_OH * 2);  // first input row

    // ---- stage input rows for all 5 objects, 3 channels (zero-pad right & bottom) ----
    for (int idx = tid; idx < NOBJ * CIN * IN_ROWS * LDS_STRIDE; idx += 256) {
        int col   = idx % LDS_STRIDE;
        int r     = idx / LDS_STRIDE;       // (obj*3+ci)*IN_ROWS + lr
        int lr    = r % IN_ROWS;
        int oc_ci = r / IN_ROWS;            // obj*3+ci, 0..14
        int gr    = r0 + lr;
        float v = 0.f;
        if (col < IMG_W && gr < IMG_H)
            v = g[(size_t)oc_ci * (IMG_H * IMG_W) + gr * IMG_W + col];
        sIn[idx] = v;
    }

    // ---- per-thread weights: oc = tid & 127 ----
    const int oc  = tid & 127;
    const int grp = tid >> 7;   // 0: output rows 0..1 of tile, 1: rows 2..3
    float wA[27], wB[27];
    const float* wp = conv_w + oc * 54;   // conv_w[oc][6][3][3]
    #pragma unroll
    for (int k = 0; k < 27; ++k) { wA[k] = wp[k]; wB[k] = wp[27 + k]; }
    const float bias = conv_b[oc];

    __syncthreads();

    float acc[NPAIR];
    #pragma unroll
    for (int q = 0; q < NPAIR; ++q) acc[q] = 0.f;

    // SAME padding with stride 2: pad_lo = 0, pad_hi = 1 (both dims) ->
    // output (orow, ocol) reads input rows orow*2..+2, cols ocol*2..+2.
    for (int orow = grp * 2; orow < grp * 2 + 2; ++orow) {
        const int lr0 = orow * 2;
        for (int ocol = 0; ocol < OW; ++ocol) {
            const int lc0 = ocol * 2;
            float av[NOBJ], bv[NOBJ];
            #pragma unroll
            for (int obj = 0; obj < NOBJ; ++obj) {
                float sa = 0.f, sb = 0.f;
                #pragma unroll
                for (int ci = 0; ci < CIN; ++ci) {
                    #pragma unroll
                    for (int kh = 0; kh < 3; ++kh) {
                        const float* rp = &sIn[((obj * CIN + ci) * IN_ROWS + lr0 + kh) * LDS_STRIDE + lc0];
                        float x0 = rp[0], x1 = rp[1], x2 = rp[2];
                        const int wi = ci * 9 + kh * 3;
                        sa += x0 * wA[wi] + x1 * wA[wi + 1] + x2 * wA[wi + 2];
                        sb += x0 * wB[wi] + x1 * wB[wi + 1] + x2 * wB[wi + 2];
                    }
                }
                av[obj] = sa + bias;   // fold bias into A-half
                bv[obj] = sb;
            }
            #pragma unroll
            for (int i = 0; i < NOBJ; ++i) {
                #pragma unroll
                for (int j = 0; j < NOBJ; ++j) {
                    float v = av[i] + bv[j];
                    acc[i * NOBJ + j] += fmaxf(v, 0.f);
                }
            }
        }
    }

    // ---- accumulate partial sums to global (coalesced across oc) ----
    float* sp = S + ((size_t)(src * BQ + b) * NPAIR) * OC + oc;
    #pragma unroll
    for (int q = 0; q < NPAIR; ++q)
        atomicAdd(&sp[q * OC], acc[q]);
}

__global__ __launch_bounds__(256) void finalize_kernel(
    const float* __restrict__ S,
    const float* __restrict__ w2,
    const float* __restrict__ b2,
    const float* __restrict__ temp,
    float* __restrict__ out)
{
    int idx = blockIdx.x * blockDim.x + threadIdx.x;  // 0 .. 2*1600*4-1
    if (idx >= 2 * 1600 * PP) return;
    int p   = idx & 3;
    int t   = (idx >> 2) % 1600;
    int src = idx / (1600 * PP);
    const float* s = S + ((size_t)(src * 1600 + t)) * OC + p * CONV_OUT;
    float sum = 0.f;
    #pragma unroll
    for (int c = 0; c < CONV_OUT; ++c) sum += s[c] * w2[p * CONV_OUT + c];
    float logit = sum * (1.0f / (OH * OW)) + b2[p];
    float x = logit / temp[0];
    out[idx] = 1.0f / (1.0f + expf(-x));
}

__global__ __launch_bounds__(256) void adj_kernel(float* __restrict__ out)
{
    int idx = blockIdx.x * blockDim.x + threadIdx.x;
    if (idx >= BQ * 1600) return;
    int b = idx / 1600;
    int t = idx - b * 1600;
    out[idx] = (t / NPAIR == b) ? 1.0f : 0.0f;
}

extern "C" void kernel_launch(void* const* d_in, const int* in_sizes, int n_in,
                              void* d_out, int out_size, void* d_ws, size_t ws_size,
                              hipStream_t stream)
{
    const float* state      = (const float*)d_in[0];
    const float* state_next = (const float*)d_in[1];
    const float* conv_w     = (const float*)d_in[2];
    const float* conv_b     = (const float*)d_in[3];
    const float* w2         = (const float*)d_in[4];
    const float* b2         = (const float*)d_in[5];
    // d_in[6] = n_obj (unused: always 5)
    const float* temp       = (const float*)d_in[7];

    float* out = (float*)d_out;
    float* S   = (float*)d_ws;

    const size_t sbytes = (size_t)2 * BQ * NPAIR * OC * sizeof(float);
    hipMemsetAsync(S, 0, sbytes, stream);

    dim3 grid1(NTILES, BQ, 2);
    conv_pair_reduce<<<grid1, 256, 0, stream>>>(state, state_next, conv_w, conv_b, S);

    finalize_kernel<<<(2 * 1600 * PP + 255) / 256, 256, 0, stream>>>(S, w2, b2, temp, out);
    adj_kernel<<<(BQ * 1600 + 255) / 256, 256, 0, stream>>>(out + 2 * 1600 * PP);
}